// Round 4
// baseline (1364.669 us; speedup 1.0000x reference)
//
#include <hip/hip_runtime.h>

typedef _Float16 h2v __attribute__((ext_vector_type(2)));
typedef _Float16 h4v __attribute__((ext_vector_type(4)));
typedef _Float16 h8v __attribute__((ext_vector_type(8)));
typedef float    f4v __attribute__((ext_vector_type(4)));
typedef unsigned int u32;

#define RSTRIDE 272              // halves per padded row (256 + 16 pad) -> 544 B
#define RBYTES  139264           // 256*272*2
#define P_OFF   139264
#define HS_OFF  141312
#define CS_OFF  141824
#define LDS_TOTAL 142336

__device__ inline f4v mfma16(h8v a, h8v b, f4v c) {
  return __builtin_amdgcn_mfma_f32_16x16x32_f16(a, b, c, 0, 0, 0);
}

__device__ inline float dot2f(u32 a, u32 b, float c) {
#if __has_builtin(__builtin_amdgcn_fdot2)
  return __builtin_amdgcn_fdot2(__builtin_bit_cast(h2v, a), __builtin_bit_cast(h2v, b), c, false);
#else
  h2v av = __builtin_bit_cast(h2v, a), bv = __builtin_bit_cast(h2v, b);
  return c + (float)av[0] * (float)bv[0] + (float)av[1] * (float)bv[1];
#endif
}

// Build padded/transposed fp16 copies of the shared matrices.
__global__ void prep_k(const float* __restrict__ Ww, const float* __restrict__ Wu,
                       const float* __restrict__ Wv, _Float16* __restrict__ wvt,
                       _Float16* __restrict__ wup, _Float16* __restrict__ wwh)
{
  int j = blockIdx.x, k = threadIdx.x;
  wvt[j * RSTRIDE + k] = (_Float16)Wv[k * 256 + j];   // WvT[j][k] = Wv[k][j]
  wup[j * RSTRIDE + k] = (_Float16)Wu[j * 256 + k];   // Wu padded row-major
  wwh[j * 256 + k]     = (_Float16)Ww[j * 256 + k];   // Ww plain row-major fp16
  if (k < 16) {
    wvt[j * RSTRIDE + 256 + k] = (_Float16)0.f;
    wup[j * RSTRIDE + 256 + k] = (_Float16)0.f;
  }
}

// out[b,i] = sum_j M[i,j] * V[b,j]   (beta = Ww@b ; final x = Wv@c)
__global__ void matvec_k(const float* __restrict__ M, const float* __restrict__ V,
                         float* __restrict__ out)
{
  __shared__ float vb[256];
  int b = blockIdx.x, i = threadIdx.x;
  vb[i] = V[(size_t)b * 256 + i];
  __syncthreads();
  float a0 = 0.f;
#pragma unroll 8
  for (int j = 0; j < 256; j += 4) {
    f4v m = *(const f4v*)(M + (size_t)i * 256 + j);
    a0 += m[0] * vb[j] + m[1] * vb[j + 1] + m[2] * vb[j + 2] + m[3] * vb[j + 3];
  }
  out[(size_t)b * 256 + i] = a0;
}

// Fragment loaders: pass the ROW-BASE pointer only; kk/g offsets applied HERE
// exactly once. (Round-3 bug: call sites double-added 4*g.)
#define LDA(base, kk, dst) { \
    f4v lo_ = *(const f4v*)((base) + (kk)*32 + 4*g); \
    f4v hi_ = *(const f4v*)((base) + (kk)*32 + 16 + 4*g); \
    dst[0]=(_Float16)lo_[0]; dst[1]=(_Float16)lo_[1]; dst[2]=(_Float16)lo_[2]; dst[3]=(_Float16)lo_[3]; \
    dst[4]=(_Float16)hi_[0]; dst[5]=(_Float16)hi_[1]; dst[6]=(_Float16)hi_[2]; dst[7]=(_Float16)hi_[3]; }

#define LDH(basep, kk, dst) { \
    h4v lo_ = *(const h4v*)((basep) + (kk)*32 + 4*g); \
    h4v hi_ = *(const h4v*)((basep) + (kk)*32 + 16 + 4*g); \
    dst = __builtin_shufflevector(lo_, hi_, 0, 1, 2, 3, 4, 5, 6, 7); }

// ---------------- K1: Tt[b,j,t] = sum_k w[b,t,k] * WvT[j,k] ----------------
__global__ __launch_bounds__(512, 2) void gemm1_k(
    const float* __restrict__ w, const _Float16* __restrict__ wvt,
    _Float16* __restrict__ TG)
{
  const int tid = threadIdx.x;
  const int wv = tid >> 6, lane = tid & 63, g = lane >> 4, l15 = lane & 15;
  const int B = blockIdx.x;

  f4v acc[2][16];
#pragma unroll
  for (int mt = 0; mt < 2; ++mt)
#pragma unroll
    for (int nt = 0; nt < 16; ++nt) acc[mt][nt] = f4v{0.f, 0.f, 0.f, 0.f};

  const float* gb0 = w + (size_t)B * 65536 + (size_t)(wv * 32 + l15) * 256;
  const float* gb1 = gb0 + 16 * 256;
  h8v a0c, a1c, a0n, a1n;
  LDA(gb0, 0, a0c); LDA(gb1, 0, a1c);
  for (int kk = 0; kk < 8; ++kk) {
    if (kk < 7) { LDA(gb0, kk + 1, a0n); LDA(gb1, kk + 1, a1n); }
#pragma unroll
    for (int nt = 0; nt < 16; ++nt) {
      const _Float16* bp = wvt + (size_t)(nt * 16 + l15) * RSTRIDE;  // row base only
      h8v bf; LDH(bp, kk, bf);
      acc[0][nt] = mfma16(a0c, bf, acc[0][nt]);
      acc[1][nt] = mfma16(a1c, bf, acc[1][nt]);
    }
    a0c = a0n; a1c = a1n;
  }

  _Float16* out = TG + (size_t)B * 65536;
#pragma unroll
  for (int mt = 0; mt < 2; ++mt)
#pragma unroll
    for (int nt = 0; nt < 16; ++nt) {
      int n = nt * 16 + l15;
      int m0 = wv * 32 + mt * 16 + g * 4;
      f4v a = acc[mt][nt];
      h4v t4; t4[0] = (_Float16)a[0]; t4[1] = (_Float16)a[1];
      t4[2] = (_Float16)a[2]; t4[3] = (_Float16)a[3];
      *(h4v*)(out + (size_t)n * 256 + m0) = t4;   // Tt[b, j=n, t=m]
    }
}

// ---------------- K2: G[b,i,j] = sum_t Tt[b,j,t] * Ww[i,t]  (IN-PLACE) -----
__global__ __launch_bounds__(512, 2) void gemm2_k(
    const _Float16* __restrict__ wwh, _Float16* __restrict__ TG)
{
  const int tid = threadIdx.x;
  const int wv = tid >> 6, lane = tid & 63, g = lane >> 4, l15 = lane & 15;
  const int B = blockIdx.x;
  _Float16* base = TG + (size_t)B * 65536;

  f4v acc[2][16];
#pragma unroll
  for (int mt = 0; mt < 2; ++mt)
#pragma unroll
    for (int nt = 0; nt < 16; ++nt) acc[mt][nt] = f4v{0.f, 0.f, 0.f, 0.f};

  const _Float16* ar0 = base + (size_t)(wv * 32 + l15) * 256;
  const _Float16* ar1 = ar0 + 16 * 256;
  h8v a0c, a1c, a0n, a1n;
  LDH(ar0, 0, a0c); LDH(ar1, 0, a1c);
  for (int kk = 0; kk < 8; ++kk) {
    if (kk < 7) { LDH(ar0, kk + 1, a0n); LDH(ar1, kk + 1, a1n); }
#pragma unroll
    for (int nt = 0; nt < 16; ++nt) {
      const _Float16* bp = wwh + (size_t)(nt * 16 + l15) * 256;     // row base only
      h8v bf; LDH(bp, kk, bf);
      acc[0][nt] = mfma16(a0c, bf, acc[0][nt]);
      acc[1][nt] = mfma16(a1c, bf, acc[1][nt]);
    }
    a0c = a0n; a1c = a1n;
  }

  __syncthreads();   // all Tt reads complete before overwriting with G

#pragma unroll
  for (int mt = 0; mt < 2; ++mt)
#pragma unroll
    for (int nt = 0; nt < 16; ++nt) {
      int n = nt * 16 + l15;              // i
      int m0 = wv * 32 + mt * 16 + g * 4; // j
      f4v a = acc[mt][nt];
      h4v t4; t4[0] = (_Float16)a[0]; t4[1] = (_Float16)a[1];
      t4[2] = (_Float16)a[2]; t4[3] = (_Float16)a[3];
      *(h4v*)(base + (size_t)n * 256 + m0) = t4;  // G[b, i, j]
    }
}

// ---------------- K3: 20-step recurrence, G/Wu in registers ----------------
__global__ __launch_bounds__(512, 2) void recur_k(
    const _Float16* __restrict__ TG, const _Float16* __restrict__ wup,
    const float* __restrict__ beta, float* __restrict__ cout)
{
  __shared__ float P[512];
  __shared__ _Float16 HS[256];
  __shared__ _Float16 CS[256];
  const int tid = threadIdx.x;
  const int i = tid & 255, h2 = tid >> 8, B = blockIdx.x;

  uint4 gq[16], wq[16];
  const uint4* grow = (const uint4*)(TG + (size_t)B * 65536 + (size_t)i * 256 + h2 * 128);
  const uint4* wrow = (const uint4*)(wup + (size_t)i * RSTRIDE + h2 * 128);
#pragma unroll
  for (int q = 0; q < 16; ++q) { gq[q] = grow[q]; wq[q] = wrow[q]; }
  float my_beta = beta[(size_t)B * 256 + i];

  if (tid < 256) HS[tid] = (_Float16)0.f; else CS[tid - 256] = (_Float16)0.f;
  float cm = 0.f;
  __syncthreads();

  const uint4* hrow = (const uint4*)((const char*)HS + h2 * 256);
  const uint4* crow = (const uint4*)((const char*)CS + h2 * 256);

  for (int t = 0; t < 20; ++t) {
    float au[4] = {0.f, 0.f, 0.f, 0.f};
    float ag[4] = {0.f, 0.f, 0.f, 0.f};
#pragma unroll
    for (int q = 0; q < 16; ++q) {
      uint4 wu4 = wq[q];
      uint4 gg  = gq[q];
      uint4 hv  = hrow[q];
      uint4 cv  = crow[q];
      float a = au[q & 3], e = ag[q & 3];
      a = dot2f(wu4.x, hv.x, a);
      a = dot2f(wu4.y, hv.y, a);
      a = dot2f(wu4.z, hv.z, a);
      a = dot2f(wu4.w, hv.w, a);
      e = dot2f(gg.x, cv.x, e);
      e = dot2f(gg.y, cv.y, e);
      e = dot2f(gg.z, cv.z, e);
      e = dot2f(gg.w, cv.w, e);
      au[q & 3] = a; ag[q & 3] = e;
    }
    float auf = (au[0] + au[1]) + (au[2] + au[3]);
    float agf = (ag[0] + ag[1]) + (ag[2] + ag[3]);
    P[tid] = (auf - agf) * 128.f;   // descale 2^7
    __syncthreads();
    float y = my_beta + P[i] + P[i + 256];
    float hval = fmaxf(y, 0.f);
    if (h2 == 0) {
      cm += hval;
      HS[i] = (_Float16)(hval * 0.0078125f);  // * 2^-7
      CS[i] = (_Float16)(cm * 0.0078125f);
    }
    __syncthreads();
  }
  if (h2 == 0) cout[(size_t)B * 256 + i] = cm;
}

// ---------------- Fallback: round-2 fused mega-kernel (small ws) -----------
__global__ __launch_bounds__(512, 2) void rnn_mega(
    const float* __restrict__ w, const float* __restrict__ beta,
    const _Float16* __restrict__ wvt, const _Float16* __restrict__ wup,
    const _Float16* __restrict__ wwh, float* __restrict__ cout)
{
  extern __shared__ char smem[];
  _Float16* reg = (_Float16*)smem;
  float*    P   = (float*)(smem + P_OFF);
  _Float16* HS  = (_Float16*)(smem + HS_OFF);
  _Float16* CS  = (_Float16*)(smem + CS_OFF);

  const int tid  = threadIdx.x;
  const int wv   = tid >> 6;
  const int lane = tid & 63;
  const int g    = lane >> 4;
  const int l15  = lane & 15;
  const int B    = blockIdx.x;

  {
    const uint4* src = (const uint4*)wvt;
    uint4* dst = (uint4*)smem;
#pragma unroll
    for (int r = 0; r < 17; ++r) dst[r * 512 + tid] = src[r * 512 + tid];
  }
  __syncthreads();

  f4v acc[2][16];
#pragma unroll
  for (int mt = 0; mt < 2; ++mt)
#pragma unroll
    for (int nt = 0; nt < 16; ++nt) acc[mt][nt] = f4v{0.f, 0.f, 0.f, 0.f};

  const float* gb0 = w + (size_t)B * 65536 + (size_t)(wv * 32 + l15) * 256;
  const float* gb1 = gb0 + 16 * 256;
  h8v a0c, a1c, a0n, a1n;
  LDA(gb0, 0, a0c); LDA(gb1, 0, a1c);
  for (int kk = 0; kk < 8; ++kk) {
    if (kk < 7) { LDA(gb0, kk + 1, a0n); LDA(gb1, kk + 1, a1n); }
#pragma unroll
    for (int nt = 0; nt < 16; ++nt) {
      const _Float16* bp = reg + (nt * 16 + l15) * RSTRIDE;          // row base only
      h8v bf; LDH(bp, kk, bf);
      acc[0][nt] = mfma16(a0c, bf, acc[0][nt]);
      acc[1][nt] = mfma16(a1c, bf, acc[1][nt]);
    }
    a0c = a0n; a1c = a1n;
  }
  __syncthreads();
#pragma unroll
  for (int mt = 0; mt < 2; ++mt)
#pragma unroll
    for (int nt = 0; nt < 16; ++nt) {
      int n = nt * 16 + l15;
      int m0 = wv * 32 + mt * 16 + g * 4;
      f4v a = acc[mt][nt];
      h4v t; t[0] = (_Float16)a[0]; t[1] = (_Float16)a[1]; t[2] = (_Float16)a[2]; t[3] = (_Float16)a[3];
      *(h4v*)(reg + n * RSTRIDE + m0) = t;
      acc[mt][nt] = f4v{0.f, 0.f, 0.f, 0.f};
    }
  __syncthreads();

  for (int kk = 0; kk < 8; ++kk) {
    const _Float16* ap0 = reg + (wv * 32 + l15) * RSTRIDE;           // row base only
    const _Float16* ap1 = ap0 + 16 * RSTRIDE;
    h8v a20, a21; LDH(ap0, kk, a20); LDH(ap1, kk, a21);
#pragma unroll
    for (int nt = 0; nt < 16; ++nt) {
      const _Float16* b2p = wwh + (nt * 16 + l15) * 256;             // row base only
      h8v bf; LDH(b2p, kk, bf);
      acc[0][nt] = mfma16(a20, bf, acc[0][nt]);
      acc[1][nt] = mfma16(a21, bf, acc[1][nt]);
    }
  }
  __syncthreads();
#pragma unroll
  for (int mt = 0; mt < 2; ++mt)
#pragma unroll
    for (int nt = 0; nt < 16; ++nt) {
      int n = nt * 16 + l15;
      int m0 = wv * 32 + mt * 16 + g * 4;
      f4v a = acc[mt][nt];
      h4v t; t[0] = (_Float16)a[0]; t[1] = (_Float16)a[1]; t[2] = (_Float16)a[2]; t[3] = (_Float16)a[3];
      *(h4v*)(reg + n * RSTRIDE + m0) = t;
    }
  __syncthreads();

  const int i  = tid & 255;
  const int h2 = tid >> 8;
  uint4 gq[16];
#pragma unroll
  for (int q = 0; q < 16; ++q)
    gq[q] = *(const uint4*)(smem + i * 544 + h2 * 256 + q * 16);
  float my_beta = beta[(size_t)B * 256 + i];

  uint4 wq[16];
  {
    const uint4* wrow = (const uint4*)(wup + (size_t)i * RSTRIDE) + h2 * 16;
#pragma unroll
    for (int q = 0; q < 16; ++q) wq[q] = wrow[q];
  }

  if (tid < 256) HS[tid] = (_Float16)0.f; else CS[tid - 256] = (_Float16)0.f;
  float cm = 0.f;
  __syncthreads();

  const uint4* hrow = (const uint4*)((const char*)HS + h2 * 256);
  const uint4* crow = (const uint4*)((const char*)CS + h2 * 256);

  for (int t = 0; t < 20; ++t) {
    float au[4] = {0.f, 0.f, 0.f, 0.f};
    float ag[4] = {0.f, 0.f, 0.f, 0.f};
#pragma unroll
    for (int q = 0; q < 16; ++q) {
      uint4 wu4 = wq[q];
      uint4 gg  = gq[q];
      uint4 hv  = hrow[q];
      uint4 cv  = crow[q];
      float a = au[q & 3], e = ag[q & 3];
      a = dot2f(wu4.x, hv.x, a);
      a = dot2f(wu4.y, hv.y, a);
      a = dot2f(wu4.z, hv.z, a);
      a = dot2f(wu4.w, hv.w, a);
      e = dot2f(gg.x, cv.x, e);
      e = dot2f(gg.y, cv.y, e);
      e = dot2f(gg.z, cv.z, e);
      e = dot2f(gg.w, cv.w, e);
      au[q & 3] = a; ag[q & 3] = e;
    }
    float auf = (au[0] + au[1]) + (au[2] + au[3]);
    float agf = (ag[0] + ag[1]) + (ag[2] + ag[3]);
    P[tid] = (auf - agf) * 128.f;
    __syncthreads();
    float y = my_beta + P[i] + P[i + 256];
    float hval = fmaxf(y, 0.f);
    if (h2 == 0) {
      cm += hval;
      HS[i] = (_Float16)(hval * 0.0078125f);
      CS[i] = (_Float16)(cm * 0.0078125f);
    }
    __syncthreads();
  }
  if (h2 == 0) cout[(size_t)B * 256 + i] = cm;
}

extern "C" void kernel_launch(void* const* d_in, const int* in_sizes, int n_in,
                              void* d_out, int out_size, void* d_ws, size_t ws_size,
                              hipStream_t stream)
{
  const float* w  = (const float*)d_in[0];
  const float* b  = (const float*)d_in[1];
  const float* Ww = (const float*)d_in[2];
  const float* Wu = (const float*)d_in[3];
  const float* Wv = (const float*)d_in[4];

  char* ws = (char*)d_ws;
  float*    beta = (float*)(ws);
  float*    cbuf = (float*)(ws + (size_t)2 * 1024 * 1024);
  _Float16* wvt  = (_Float16*)(ws + (size_t)4 * 1024 * 1024);
  _Float16* wup  = (_Float16*)(ws + (size_t)4 * 1024 * 1024 + RBYTES);
  _Float16* wwh  = (_Float16*)(ws + (size_t)4 * 1024 * 1024 + 2 * (size_t)RBYTES);
  _Float16* TG   = (_Float16*)(ws + (size_t)8 * 1024 * 1024);

  (void)in_sizes; (void)n_in; (void)out_size;

  prep_k<<<256, 256, 0, stream>>>(Ww, Wu, Wv, wvt, wup, wwh);
  matvec_k<<<2048, 256, 0, stream>>>(Ww, b, beta);                 // beta = Ww @ b

  const size_t need = (size_t)8 * 1024 * 1024 + (size_t)268435456;  // 8MB + 256MiB
  if (ws_size >= need) {
    gemm1_k<<<2048, 512, 0, stream>>>(w, wvt, TG);
    gemm2_k<<<2048, 512, 0, stream>>>(wwh, TG);
    recur_k<<<2048, 512, 0, stream>>>(TG, wup, beta, cbuf);
  } else {
    hipFuncSetAttribute((const void*)rnn_mega,
                        hipFuncAttributeMaxDynamicSharedMemorySize, LDS_TOTAL);
    rnn_mega<<<2048, 512, LDS_TOTAL, stream>>>(w, beta, wvt, wup, wwh, cbuf);
  }

  matvec_k<<<2048, 256, 0, stream>>>(Wv, cbuf, (float*)d_out);     // x = Wv @ c
}

// Round 5
// 1062.906 us; speedup vs baseline: 1.2839x; 1.2839x over previous
//
#include <hip/hip_runtime.h>

typedef _Float16 h2v __attribute__((ext_vector_type(2)));
typedef _Float16 h4v __attribute__((ext_vector_type(4)));
typedef _Float16 h8v __attribute__((ext_vector_type(8)));
typedef float    f4v __attribute__((ext_vector_type(4)));
typedef unsigned int u32;

#define RSTRIDE 264                    // halves per padded row: 528 B = 132 dw, 132%32=4 -> 2-way (free)
#define RBYTES  135168                 // 256*264*2
#define RUINT4  8448                   // RBYTES/16
#define P_OFF   135168
#define HS_OFF  137216
#define CS_OFF  137728
#define LDS_K2  138240                 // region + P(2048) + HS(512) + CS(512)
#define LDS_K1  135168

__device__ inline f4v mfma16(h8v a, h8v b, f4v c) {
  return __builtin_amdgcn_mfma_f32_16x16x32_f16(a, b, c, 0, 0, 0);
}

__device__ inline float dot2f(u32 a, u32 b, float c) {
#if __has_builtin(__builtin_amdgcn_fdot2)
  return __builtin_amdgcn_fdot2(__builtin_bit_cast(h2v, a), __builtin_bit_cast(h2v, b), c, false);
#else
  h2v av = __builtin_bit_cast(h2v, a), bv = __builtin_bit_cast(h2v, b);
  return c + (float)av[0] * (float)bv[0] + (float)av[1] * (float)bv[1];
#endif
}

// Build padded/transposed fp16 copies of the shared matrices (stride 264).
__global__ void prep_k(const float* __restrict__ Ww, const float* __restrict__ Wu,
                       const float* __restrict__ Wv, _Float16* __restrict__ wvt,
                       _Float16* __restrict__ wup, _Float16* __restrict__ wwh)
{
  int j = blockIdx.x, k = threadIdx.x;
  wvt[j * RSTRIDE + k] = (_Float16)Wv[k * 256 + j];   // WvT[j][k] = Wv[k][j]
  wup[j * RSTRIDE + k] = (_Float16)Wu[j * 256 + k];   // Wu padded row-major
  wwh[j * RSTRIDE + k] = (_Float16)Ww[j * 256 + k];   // Ww padded row-major
  if (k < 8) {
    wvt[j * RSTRIDE + 256 + k] = (_Float16)0.f;
    wup[j * RSTRIDE + 256 + k] = (_Float16)0.f;
    wwh[j * RSTRIDE + 256 + k] = (_Float16)0.f;
  }
}

// out[b,i] = sum_j M[i,j] * V[b,j]   (beta = Ww@b ; final x = Wv@c)
__global__ void matvec_k(const float* __restrict__ M, const float* __restrict__ V,
                         float* __restrict__ out)
{
  __shared__ float vb[256];
  int b = blockIdx.x, i = threadIdx.x;
  vb[i] = V[(size_t)b * 256 + i];
  __syncthreads();
  float a0 = 0.f;
#pragma unroll 8
  for (int j = 0; j < 256; j += 4) {
    f4v m = *(const f4v*)(M + (size_t)i * 256 + j);
    a0 += m[0] * vb[j] + m[1] * vb[j + 1] + m[2] * vb[j + 2] + m[3] * vb[j + 3];
  }
  out[(size_t)b * 256 + i] = a0;
}

// Fragment loaders: ROW-BASE pointer only; kk/g offsets applied exactly once.
#define LDA(base, kk, dst) { \
    f4v lo_ = *(const f4v*)((base) + (kk)*32 + 4*g); \
    f4v hi_ = *(const f4v*)((base) + (kk)*32 + 16 + 4*g); \
    dst[0]=(_Float16)lo_[0]; dst[1]=(_Float16)lo_[1]; dst[2]=(_Float16)lo_[2]; dst[3]=(_Float16)lo_[3]; \
    dst[4]=(_Float16)hi_[0]; dst[5]=(_Float16)hi_[1]; dst[6]=(_Float16)hi_[2]; dst[7]=(_Float16)hi_[3]; }

#define LDH(basep, kk, dst) { \
    h4v lo_ = *(const h4v*)((basep) + (kk)*32 + 4*g); \
    h4v hi_ = *(const h4v*)((basep) + (kk)*32 + 16 + 4*g); \
    dst = __builtin_shufflevector(lo_, hi_, 0, 1, 2, 3, 4, 5, 6, 7); }

#define STAGE_LDS(srcp) { \
    const uint4* src_ = (const uint4*)(srcp); \
    uint4* dst_ = (uint4*)smem; \
    for (int it_ = 0; it_ < 17; ++it_) { \
      int idx_ = it_ * 512 + tid; \
      if (idx_ < RUINT4) dst_[idx_] = src_[idx_]; \
    } }

// ---------------- K1: Tt[b,j,t] = sum_k w[b,t,k] * WvT[j,k] ----------------
// 512 blocks x 4 batches. WvT staged to LDS ONCE; batch loop is barrier-free.
__global__ __launch_bounds__(512, 2) void gemm1_k(
    const float* __restrict__ w, const _Float16* __restrict__ wvt,
    _Float16* __restrict__ TG)
{
  extern __shared__ char smem[];
  const _Float16* breg = (const _Float16*)smem;
  const int tid = threadIdx.x;
  const int wv = tid >> 6, lane = tid & 63, g = lane >> 4, l15 = lane & 15;

  STAGE_LDS(wvt);
  __syncthreads();

  for (int bi = 0; bi < 4; ++bi) {
    const int B = blockIdx.x * 4 + bi;

    f4v acc[2][16];
#pragma unroll
    for (int mt = 0; mt < 2; ++mt)
#pragma unroll
      for (int nt = 0; nt < 16; ++nt) acc[mt][nt] = f4v{0.f, 0.f, 0.f, 0.f};

    const float* gb0 = w + (size_t)B * 65536 + (size_t)(wv * 32 + l15) * 256;
    const float* gb1 = gb0 + 16 * 256;
    h8v a0c, a1c, a0n, a1n;
    LDA(gb0, 0, a0c); LDA(gb1, 0, a1c);
    for (int kk = 0; kk < 8; ++kk) {
      if (kk < 7) { LDA(gb0, kk + 1, a0n); LDA(gb1, kk + 1, a1n); }
#pragma unroll
      for (int nt = 0; nt < 16; ++nt) {
        const _Float16* bp = breg + (nt * 16 + l15) * RSTRIDE;   // row base only
        h8v bf; LDH(bp, kk, bf);
        acc[0][nt] = mfma16(a0c, bf, acc[0][nt]);
        acc[1][nt] = mfma16(a1c, bf, acc[1][nt]);
      }
      a0c = a0n; a1c = a1n;
    }

    _Float16* out = TG + (size_t)B * 65536;
#pragma unroll
    for (int mt = 0; mt < 2; ++mt)
#pragma unroll
      for (int nt = 0; nt < 16; ++nt) {
        int n = nt * 16 + l15;
        int m0 = wv * 32 + mt * 16 + g * 4;
        f4v a = acc[mt][nt];
        h4v t4; t4[0] = (_Float16)a[0]; t4[1] = (_Float16)a[1];
        t4[2] = (_Float16)a[2]; t4[3] = (_Float16)a[3];
        *(h4v*)(out + (size_t)n * 256 + m0) = t4;   // Tt[b, j=n, t=m]
      }
  }
}

// ---------- K2 fused: G = Ww @ T (A=Tt global, B=Ww LDS) + 20-step recurrence
// One block per batch; G lives in LDS-bounce -> registers, never HBM.
__global__ __launch_bounds__(512, 2) void g_recur_k(
    const _Float16* __restrict__ TG, const _Float16* __restrict__ wwh,
    const _Float16* __restrict__ wup, const float* __restrict__ beta,
    float* __restrict__ cout)
{
  extern __shared__ char smem[];
  _Float16* reg = (_Float16*)smem;                 // Ww staging, then G bounce
  float*    P   = (float*)(smem + P_OFF);
  _Float16* HS  = (_Float16*)(smem + HS_OFF);
  _Float16* CS  = (_Float16*)(smem + CS_OFF);

  const int tid = threadIdx.x;
  const int wv = tid >> 6, lane = tid & 63, g = lane >> 4, l15 = lane & 15;
  const int B = blockIdx.x;

  STAGE_LDS(wwh);
  __syncthreads();

  f4v acc[2][16];
#pragma unroll
  for (int mt = 0; mt < 2; ++mt)
#pragma unroll
    for (int nt = 0; nt < 16; ++nt) acc[mt][nt] = f4v{0.f, 0.f, 0.f, 0.f};

  // GEMM2: C[j,i] = sum_t Tt[b,j,t] * Ww[i,t]  ( = G[i,j] )
  const _Float16* ar0 = TG + (size_t)B * 65536 + (size_t)(wv * 32 + l15) * 256;
  const _Float16* ar1 = ar0 + 16 * 256;
  h8v a0c, a1c, a0n, a1n;
  LDH(ar0, 0, a0c); LDH(ar1, 0, a1c);
  for (int kk = 0; kk < 8; ++kk) {
    if (kk < 7) { LDH(ar0, kk + 1, a0n); LDH(ar1, kk + 1, a1n); }
#pragma unroll
    for (int nt = 0; nt < 16; ++nt) {
      const _Float16* bp = reg + (nt * 16 + l15) * RSTRIDE;      // row base only
      h8v bf; LDH(bp, kk, bf);
      acc[0][nt] = mfma16(a0c, bf, acc[0][nt]);
      acc[1][nt] = mfma16(a1c, bf, acc[1][nt]);
    }
    a0c = a0n; a1c = a1n;
  }
  __syncthreads();   // all Ww LDS reads done before overwriting with G

  // bounce G[i=n][j=m] into the region
#pragma unroll
  for (int mt = 0; mt < 2; ++mt)
#pragma unroll
    for (int nt = 0; nt < 16; ++nt) {
      int n = nt * 16 + l15;
      int m0 = wv * 32 + mt * 16 + g * 4;
      f4v a = acc[mt][nt];
      h4v t4; t4[0] = (_Float16)a[0]; t4[1] = (_Float16)a[1];
      t4[2] = (_Float16)a[2]; t4[3] = (_Float16)a[3];
      *(h4v*)(reg + n * RSTRIDE + m0) = t4;
    }
  __syncthreads();

  // pull my half-row of G into registers
  const int i  = tid & 255;
  const int h2 = tid >> 8;
  uint4 gq[16], wq[16];
#pragma unroll
  for (int q = 0; q < 16; ++q)
    gq[q] = *(const uint4*)(smem + i * 528 + h2 * 256 + q * 16);
  {
    const uint4* wrow = (const uint4*)(wup + (size_t)i * RSTRIDE) + h2 * 16;
#pragma unroll
    for (int q = 0; q < 16; ++q) wq[q] = wrow[q];
  }
  float my_beta = beta[(size_t)B * 256 + i];

  if (tid < 256) HS[tid] = (_Float16)0.f; else CS[tid - 256] = (_Float16)0.f;
  float cm = 0.f;
  __syncthreads();

  const uint4* hrow = (const uint4*)((const char*)HS + h2 * 256);
  const uint4* crow = (const uint4*)((const char*)CS + h2 * 256);

  for (int t = 0; t < 20; ++t) {
    float au[4] = {0.f, 0.f, 0.f, 0.f};
    float ag[4] = {0.f, 0.f, 0.f, 0.f};
#pragma unroll
    for (int q = 0; q < 16; ++q) {
      uint4 wu4 = wq[q];
      uint4 gg  = gq[q];
      uint4 hv  = hrow[q];
      uint4 cv  = crow[q];
      float a = au[q & 3], e = ag[q & 3];
      a = dot2f(wu4.x, hv.x, a);
      a = dot2f(wu4.y, hv.y, a);
      a = dot2f(wu4.z, hv.z, a);
      a = dot2f(wu4.w, hv.w, a);
      e = dot2f(gg.x, cv.x, e);
      e = dot2f(gg.y, cv.y, e);
      e = dot2f(gg.z, cv.z, e);
      e = dot2f(gg.w, cv.w, e);
      au[q & 3] = a; ag[q & 3] = e;
    }
    float auf = (au[0] + au[1]) + (au[2] + au[3]);
    float agf = (ag[0] + ag[1]) + (ag[2] + ag[3]);
    P[tid] = (auf - agf) * 128.f;   // descale 2^7
    __syncthreads();
    float y = my_beta + P[i] + P[i + 256];
    float hval = fmaxf(y, 0.f);
    if (h2 == 0) {
      cm += hval;
      HS[i] = (_Float16)(hval * 0.0078125f);  // * 2^-7
      CS[i] = (_Float16)(cm * 0.0078125f);
    }
    __syncthreads();
  }
  if (h2 == 0) cout[(size_t)B * 256 + i] = cm;
}

extern "C" void kernel_launch(void* const* d_in, const int* in_sizes, int n_in,
                              void* d_out, int out_size, void* d_ws, size_t ws_size,
                              hipStream_t stream)
{
  const float* w  = (const float*)d_in[0];
  const float* b  = (const float*)d_in[1];
  const float* Ww = (const float*)d_in[2];
  const float* Wu = (const float*)d_in[3];
  const float* Wv = (const float*)d_in[4];

  char* ws = (char*)d_ws;
  float*    beta = (float*)(ws);
  float*    cbuf = (float*)(ws + (size_t)2 * 1024 * 1024);
  _Float16* wvt  = (_Float16*)(ws + (size_t)4 * 1024 * 1024);
  _Float16* wup  = (_Float16*)(ws + (size_t)4 * 1024 * 1024 + RBYTES);
  _Float16* wwh  = (_Float16*)(ws + (size_t)4 * 1024 * 1024 + 2 * (size_t)RBYTES);
  _Float16* TG   = (_Float16*)(ws + (size_t)8 * 1024 * 1024);

  (void)in_sizes; (void)n_in; (void)out_size; (void)ws_size;

  hipFuncSetAttribute((const void*)gemm1_k,
                      hipFuncAttributeMaxDynamicSharedMemorySize, LDS_K1);
  hipFuncSetAttribute((const void*)g_recur_k,
                      hipFuncAttributeMaxDynamicSharedMemorySize, LDS_K2);

  prep_k<<<256, 256, 0, stream>>>(Ww, Wu, Wv, wvt, wup, wwh);
  matvec_k<<<2048, 256, 0, stream>>>(Ww, b, beta);                  // beta = Ww @ b
  gemm1_k<<<512, 512, LDS_K1, stream>>>(w, wvt, TG);                // Tt = (w_b @ Wv)^T
  g_recur_k<<<2048, 512, LDS_K2, stream>>>(TG, wwh, wup, beta, cbuf); // G + recurrence
  matvec_k<<<2048, 256, 0, stream>>>(Wv, cbuf, (float*)d_out);      // x = Wv @ c
}

// Round 6
// 899.458 us; speedup vs baseline: 1.5172x; 1.1817x over previous
//
#include <hip/hip_runtime.h>

typedef _Float16 h2v __attribute__((ext_vector_type(2)));
typedef _Float16 h4v __attribute__((ext_vector_type(4)));
typedef _Float16 h8v __attribute__((ext_vector_type(8)));
typedef float    f4v __attribute__((ext_vector_type(4)));
typedef unsigned int u32;
typedef unsigned long long u64;

#define RSTRIDE 264                    // wup padded row: 528 B (2-way bank, free)
#define PK_BYTES 131072                // packed b-frag matrix: 16nt*8kk*64lane*16B
#define G_OFF   0
#define P_OFF   135168                 // G region 256*264*2
#define HS_OFF  137216
#define CS_OFF  137728
#define LDS_K2  138240
#define LDS_K1  65536                  // 2 x 32KB w-tile double buffer

__device__ inline f4v mfma16(h8v a, h8v b, f4v c) {
  return __builtin_amdgcn_mfma_f32_16x16x32_f16(a, b, c, 0, 0, 0);
}

__device__ inline float dot2f(u32 a, u32 b, float c) {
#if __has_builtin(__builtin_amdgcn_fdot2)
  return __builtin_amdgcn_fdot2(__builtin_bit_cast(h2v, a), __builtin_bit_cast(h2v, b), c, false);
#else
  h2v av = __builtin_bit_cast(h2v, a), bv = __builtin_bit_cast(h2v, b);
  return c + (float)av[0] * (float)bv[0] + (float)av[1] * (float)bv[1];
#endif
}

__device__ inline h8v cvt8(f4v lo, f4v hi) {
  h8v d;
  d[0] = (_Float16)lo[0]; d[1] = (_Float16)lo[1]; d[2] = (_Float16)lo[2]; d[3] = (_Float16)lo[3];
  d[4] = (_Float16)hi[0]; d[5] = (_Float16)hi[1]; d[6] = (_Float16)hi[2]; d[7] = (_Float16)hi[3];
  return d;
}

__device__ inline void glds16(const void* g, void* l) {
  __builtin_amdgcn_global_load_lds(
      (const __attribute__((address_space(1))) unsigned int*)g,
      (__attribute__((address_space(3))) unsigned int*)l, 16, 0, 0);
}

// ---- prep: Wu padded row-major (for recurrence row pulls) ----
__global__ void prep_k(const float* __restrict__ Wu, _Float16* __restrict__ wup)
{
  int j = blockIdx.x, k = threadIdx.x;
  wup[j * RSTRIDE + k] = (_Float16)Wu[j * 256 + k];
  if (k < 8) wup[j * RSTRIDE + 256 + k] = (_Float16)0.f;
}

// ---- prep2: pack Wv / Ww into MFMA B-fragment order ----
// dst[((nt*8+kk)*64 + lane)*8 + h] with lane=(l15,g):
//   k = kk*32 + (h<4 ? 4g+h : 16+4g+(h-4)),  j = nt*16+l15
//   mat0 (wvp): val = Wv[k][j]   (B of GEMM1 = WvT[j][k])
//   mat1 (wwp): val = Ww[j][k]   (B of GEMM2 = Ww[i=j][t=k])
__global__ void prep2_k(const float* __restrict__ Wv, const float* __restrict__ Ww,
                        _Float16* __restrict__ wvp, _Float16* __restrict__ wwp)
{
  int b = blockIdx.x;
  int mat = b >> 7, ntkk = b & 127;
  int nt = ntkk >> 3, kk = ntkk & 7;
  int tid = threadIdx.x;
  int lane = tid & 63, q = tid >> 6;
  int g2 = (lane >> 4) & 3, l15 = lane & 15;
  int j = nt * 16 + l15;
  _Float16* dst = (mat == 0 ? wvp : wwp) + ((size_t)(ntkk * 64 + lane)) * 8;
#pragma unroll
  for (int e = 0; e < 2; ++e) {
    int h = 2 * q + e;
    int k = kk * 32 + (h < 4 ? 4 * g2 + h : 16 + 4 * g2 + (h - 4));
    float val = (mat == 0) ? Wv[(size_t)k * 256 + j] : Ww[(size_t)j * 256 + k];
    dst[h] = (_Float16)val;
  }
}

// out[b,i] = sum_j M[i,j] * V[b,j]   (beta = Ww@b ; final x = Wv@c)
__global__ void matvec_k(const float* __restrict__ M, const float* __restrict__ V,
                         float* __restrict__ out)
{
  __shared__ float vb[256];
  int b = blockIdx.x, i = threadIdx.x;
  vb[i] = V[(size_t)b * 256 + i];
  __syncthreads();
  float a0 = 0.f;
#pragma unroll 8
  for (int j = 0; j < 256; j += 4) {
    f4v m = *(const f4v*)(M + (size_t)i * 256 + j);
    a0 += m[0] * vb[j] + m[1] * vb[j + 1] + m[2] * vb[j + 2] + m[3] * vb[j + 3];
  }
  out[(size_t)b * 256 + i] = a0;
}

// ---------------- K1: Tt[b,j,t] = sum_k w[b,t,k] * Wv[k,j] ----------------
// w staged via global_load_lds, column-chunk-major tile [8 chunks][256 rows]*16B.
// B-frags straight from L2 (packed wvp). Counted-vmcnt 2-phase pipeline.
#define STAGE1(bufi, kki) { \
    _Pragma("unroll") \
    for (int i_ = 0; i_ < 4; ++i_) { \
      int idx_ = i_ * 512 + tid; \
      int c_ = idx_ >> 8, r_ = idx_ & 255; \
      glds16((const char*)wb + (size_t)r_ * 1024 + (kki) * 128 + c_ * 16, \
             smem + (bufi) * 32768 + idx_ * 16); \
    } }

__global__ __launch_bounds__(512, 1) void gemm1_k(
    const float* __restrict__ w, const _Float16* __restrict__ wvp,
    _Float16* __restrict__ TG)
{
  extern __shared__ char smem[];
  const int tid = threadIdx.x;
  const int wv = tid >> 6, lane = tid & 63, g = (lane >> 4) & 3, l15 = lane & 15;
  const int B = blockIdx.x;
  const float* wb = w + (size_t)B * 65536;

  f4v acc[2][16];
#pragma unroll
  for (int mt = 0; mt < 2; ++mt)
#pragma unroll
    for (int nt = 0; nt < 16; ++nt) acc[mt][nt] = f4v{0.f, 0.f, 0.f, 0.f};

  STAGE1(0, 0);
  STAGE1(1, 1);

  const int r0 = wv * 32 + l15, r1 = r0 + 16;
  const h8v* bfbase = (const h8v*)wvp;

#pragma unroll
  for (int kk = 0; kk < 8; ++kk) {
    if (kk < 7) { asm volatile("s_waitcnt vmcnt(4)" ::: "memory"); }
    else        { asm volatile("s_waitcnt vmcnt(0)" ::: "memory"); }
    __builtin_amdgcn_s_barrier();
    asm volatile("" ::: "memory");

    const char* tb = smem + (kk & 1) * 32768;
    f4v a0l = *(const f4v*)(tb + g * 4096 + r0 * 16);
    f4v a0h = *(const f4v*)(tb + (g + 4) * 4096 + r0 * 16);
    f4v a1l = *(const f4v*)(tb + g * 4096 + r1 * 16);
    f4v a1h = *(const f4v*)(tb + (g + 4) * 4096 + r1 * 16);
    h8v a0 = cvt8(a0l, a0h);
    h8v a1 = cvt8(a1l, a1h);

    const h8v* bfp = bfbase + kk * 64 + lane;
#pragma unroll
    for (int nt = 0; nt < 16; ++nt) {
      h8v bf = bfp[nt * 512];
      acc[0][nt] = mfma16(a0, bf, acc[0][nt]);
      acc[1][nt] = mfma16(a1, bf, acc[1][nt]);
    }

    asm volatile("" ::: "memory");
    __builtin_amdgcn_s_barrier();
    asm volatile("" ::: "memory");
    if (kk < 6) { STAGE1(kk & 1, kk + 2); }
  }

  // epilogue: Tt[b, j=n, t=m]; nt outer, mt inner -> back-to-back sector fill; NT stores
  _Float16* out = TG + (size_t)B * 65536;
#pragma unroll
  for (int nt = 0; nt < 16; ++nt) {
    int n = nt * 16 + l15;
#pragma unroll
    for (int mt = 0; mt < 2; ++mt) {
      int m0 = wv * 32 + mt * 16 + g * 4;
      f4v a = acc[mt][nt];
      h4v t4; t4[0] = (_Float16)a[0]; t4[1] = (_Float16)a[1];
      t4[2] = (_Float16)a[2]; t4[3] = (_Float16)a[3];
      __builtin_nontemporal_store(__builtin_bit_cast(u64, t4),
                                  (u64*)(out + (size_t)n * 256 + m0));
    }
  }
}

// NT fragment loader for streamed Tt rows (row-base pointer; kk/g applied once)
#define LDHNT(basep, kk, dst) { \
    u64 lo_ = __builtin_nontemporal_load((const u64*)((basep) + (kk)*32 + 4*g)); \
    u64 hi_ = __builtin_nontemporal_load((const u64*)((basep) + (kk)*32 + 16 + 4*g)); \
    h4v l4_ = __builtin_bit_cast(h4v, lo_), h4_ = __builtin_bit_cast(h4v, hi_); \
    dst = __builtin_shufflevector(l4_, h4_, 0, 1, 2, 3, 4, 5, 6, 7); }

// ---------- K2 fused: G = Ww @ T (A=Tt NT-stream, B=wwp from L2) + recurrence
__global__ __launch_bounds__(512, 1) void g_recur_k(
    const _Float16* __restrict__ TG, const _Float16* __restrict__ wwp,
    const _Float16* __restrict__ wup, const float* __restrict__ beta,
    float* __restrict__ cout)
{
  extern __shared__ char smem[];
  _Float16* reg = (_Float16*)(smem + G_OFF);       // G bounce 256 x 264
  float*    P   = (float*)(smem + P_OFF);
  _Float16* HS  = (_Float16*)(smem + HS_OFF);
  _Float16* CS  = (_Float16*)(smem + CS_OFF);

  const int tid = threadIdx.x;
  const int wv = tid >> 6, lane = tid & 63, g = (lane >> 4) & 3, l15 = lane & 15;
  const int B = blockIdx.x;

  f4v acc[2][16];
#pragma unroll
  for (int mt = 0; mt < 2; ++mt)
#pragma unroll
    for (int nt = 0; nt < 16; ++nt) acc[mt][nt] = f4v{0.f, 0.f, 0.f, 0.f};

  // GEMM2: C[j,i] = sum_t Tt[b,j,t] * Ww[i,t]  ( = G[i,j] )
  const _Float16* ar0 = TG + (size_t)B * 65536 + (size_t)(wv * 32 + l15) * 256;
  const _Float16* ar1 = ar0 + 16 * 256;
  const h8v* bfbase = (const h8v*)wwp;
  h8v a0c, a1c, a0n, a1n;
  LDHNT(ar0, 0, a0c); LDHNT(ar1, 0, a1c);
#pragma unroll
  for (int kk = 0; kk < 8; ++kk) {
    if (kk < 7) { LDHNT(ar0, kk + 1, a0n); LDHNT(ar1, kk + 1, a1n); }
    const h8v* bfp = bfbase + kk * 64 + lane;
#pragma unroll
    for (int nt = 0; nt < 16; ++nt) {
      h8v bf = bfp[nt * 512];
      acc[0][nt] = mfma16(a0c, bf, acc[0][nt]);
      acc[1][nt] = mfma16(a1c, bf, acc[1][nt]);
    }
    a0c = a0n; a1c = a1n;
  }

  // bounce G[i=n][j=m] into LDS (first LDS touch -> no barrier needed before)
#pragma unroll
  for (int mt = 0; mt < 2; ++mt)
#pragma unroll
    for (int nt = 0; nt < 16; ++nt) {
      int n = nt * 16 + l15;
      int m0 = wv * 32 + mt * 16 + g * 4;
      f4v a = acc[mt][nt];
      h4v t4; t4[0] = (_Float16)a[0]; t4[1] = (_Float16)a[1];
      t4[2] = (_Float16)a[2]; t4[3] = (_Float16)a[3];
      *(h4v*)(reg + n * RSTRIDE + m0) = t4;
    }
  __syncthreads();

  // pull my half-row of G into registers; Wu half-row from global (L2-hot)
  const int i  = tid & 255;
  const int h2 = tid >> 8;
  uint4 gq[16], wq[16];
#pragma unroll
  for (int q = 0; q < 16; ++q)
    gq[q] = *(const uint4*)(smem + i * 528 + h2 * 256 + q * 16);
  {
    const uint4* wrow = (const uint4*)(wup + (size_t)i * RSTRIDE) + h2 * 16;
#pragma unroll
    for (int q = 0; q < 16; ++q) wq[q] = wrow[q];
  }
  float my_beta = beta[(size_t)B * 256 + i];

  if (tid < 256) HS[tid] = (_Float16)0.f; else CS[tid - 256] = (_Float16)0.f;
  float cm = 0.f;
  __syncthreads();

  const uint4* hrow = (const uint4*)((const char*)HS + h2 * 256);
  const uint4* crow = (const uint4*)((const char*)CS + h2 * 256);

  for (int t = 0; t < 20; ++t) {
    float au[4] = {0.f, 0.f, 0.f, 0.f};
    float ag[4] = {0.f, 0.f, 0.f, 0.f};
#pragma unroll
    for (int q = 0; q < 16; ++q) {
      uint4 wu4 = wq[q];
      uint4 gg  = gq[q];
      uint4 hv  = hrow[q];
      uint4 cv  = crow[q];
      float a = au[q & 3], e = ag[q & 3];
      a = dot2f(wu4.x, hv.x, a);
      a = dot2f(wu4.y, hv.y, a);
      a = dot2f(wu4.z, hv.z, a);
      a = dot2f(wu4.w, hv.w, a);
      e = dot2f(gg.x, cv.x, e);
      e = dot2f(gg.y, cv.y, e);
      e = dot2f(gg.z, cv.z, e);
      e = dot2f(gg.w, cv.w, e);
      au[q & 3] = a; ag[q & 3] = e;
    }
    float auf = (au[0] + au[1]) + (au[2] + au[3]);
    float agf = (ag[0] + ag[1]) + (ag[2] + ag[3]);
    P[tid] = (auf - agf) * 128.f;   // descale 2^7
    __syncthreads();
    float y = my_beta + P[i] + P[i + 256];
    float hval = fmaxf(y, 0.f);
    if (h2 == 0) {
      cm += hval;
      HS[i] = (_Float16)(hval * 0.0078125f);  // * 2^-7
      CS[i] = (_Float16)(cm * 0.0078125f);
    }
    __syncthreads();
  }
  if (h2 == 0) cout[(size_t)B * 256 + i] = cm;
}

extern "C" void kernel_launch(void* const* d_in, const int* in_sizes, int n_in,
                              void* d_out, int out_size, void* d_ws, size_t ws_size,
                              hipStream_t stream)
{
  const float* w  = (const float*)d_in[0];
  const float* b  = (const float*)d_in[1];
  const float* Ww = (const float*)d_in[2];
  const float* Wu = (const float*)d_in[3];
  const float* Wv = (const float*)d_in[4];

  char* ws = (char*)d_ws;
  float*    beta = (float*)(ws);
  float*    cbuf = (float*)(ws + (size_t)2 * 1024 * 1024);
  _Float16* wvp  = (_Float16*)(ws + (size_t)4 * 1024 * 1024);
  _Float16* wwp  = (_Float16*)(ws + (size_t)4 * 1024 * 1024 + PK_BYTES);
  _Float16* wup  = (_Float16*)(ws + (size_t)4 * 1024 * 1024 + 2 * (size_t)PK_BYTES);
  _Float16* TG   = (_Float16*)(ws + (size_t)8 * 1024 * 1024);

  (void)in_sizes; (void)n_in; (void)out_size; (void)ws_size;

  hipFuncSetAttribute((const void*)gemm1_k,
                      hipFuncAttributeMaxDynamicSharedMemorySize, LDS_K1);
  hipFuncSetAttribute((const void*)g_recur_k,
                      hipFuncAttributeMaxDynamicSharedMemorySize, LDS_K2);

  prep_k<<<256, 256, 0, stream>>>(Wu, wup);
  prep2_k<<<256, 256, 0, stream>>>(Wv, Ww, wvp, wwp);
  matvec_k<<<2048, 256, 0, stream>>>(Ww, b, beta);                    // beta = Ww @ b
  gemm1_k<<<2048, 512, LDS_K1, stream>>>(w, wvp, TG);                 // Tt = (w_b @ Wv)^T
  g_recur_k<<<2048, 512, LDS_K2, stream>>>(TG, wwp, wup, beta, cbuf); // G + recurrence
  matvec_k<<<2048, 256, 0, stream>>>(Wv, cbuf, (float*)d_out);        // x = Wv @ c
}